// Round 6
// baseline (1118.570 us; speedup 1.0000x reference)
//
#include <hip/hip_runtime.h>
#include <stdint.h>

// ---------- types / helpers ----------
using short8  = __attribute__((ext_vector_type(8))) short;
using float4v = __attribute__((ext_vector_type(4))) float;

__device__ __forceinline__ float b2f(unsigned short u) {
    union { unsigned int i; float f; } v; v.i = ((unsigned int)u) << 16; return v.f;
}
__device__ __forceinline__ unsigned short f2b(float f) {
    union { float f; unsigned int i; } v; v.f = f;
    unsigned int x = v.i;
    unsigned int r = (x + 0x7fffu + ((x >> 16) & 1u)) >> 16;   // RNE
    return (unsigned short)r;
}

__device__ __forceinline__ void gload_lds16(const void* g, void* l) {
    __builtin_amdgcn_global_load_lds((const __attribute__((address_space(1))) void*)g,
                                     (__attribute__((address_space(3))) void*)l, 16, 0, 0);
}

// ================= ELL fill, direction-split (primary) =================
// One direction per dispatch so each XCD's working slice (adj 3.2MB + cnt
// 50KB) fits its 4MB L2 -> partially-filled adjacency lines stop thrashing
// (R5: WRITE_SIZE 171MB vs ~13MB dirty lines). Edge re-reads are L3-absorbed.
__global__ __launch_bounds__(256)
void fill_ell_dir(const int* __restrict__ key, const int* __restrict__ val,
                  int* __restrict__ cnt, int* __restrict__ adj,
                  int E, int N, int nch) {
    const int NR = 8;
    int r     = blockIdx.x & (NR - 1);
    int chunk = blockIdx.x >> 3;
    int rng = (N + NR - 1) / NR;
    int lo = r * rng;
    int hi = lo + rng; if (hi > N) hi = N;
    int per = (E + nch - 1) / nch;
    int e0 = chunk * per;
    int e1 = e0 + per; if (e1 > E) e1 = E;
    for (int e = e0 + (int)threadIdx.x; e < e1; e += 256) {
        int k = __builtin_nontemporal_load(key + e);
        if (k >= lo && k < hi) {
            int v = __builtin_nontemporal_load(val + e);
            int sl = atomicAdd(cnt + k, 1);
            if (sl < 64) adj[((size_t)k << 6) + sl] = v;
        }
    }
}

// ================= CSR fallback path (if ws too small for ELL) =================
__global__ void count_deg(const int* __restrict__ src, const int* __restrict__ dst,
                          int* __restrict__ deg_h, int* __restrict__ deg_b, int E) {
    int e = blockIdx.x * blockDim.x + threadIdx.x;
    if (e < E) {
        int s = __builtin_nontemporal_load(src + e);
        int d = __builtin_nontemporal_load(dst + e);
        atomicAdd(deg_h + s, 1);
        atomicAdd(deg_b + d, 1);
    }
}
__global__ void scan1(const int* __restrict__ deg, int* __restrict__ partial, int N) {
    int t = threadIdx.x;
    int base = blockIdx.x * 1024 + t * 4;
    int s = 0;
    #pragma unroll
    for (int i = 0; i < 4; ++i) { int idx = base + i; if (idx < N) s += deg[idx]; }
    #pragma unroll
    for (int off = 32; off; off >>= 1) s += __shfl_down(s, off);
    __shared__ int sm[4];
    if ((t & 63) == 0) sm[t >> 6] = s;
    __syncthreads();
    if (t == 0) partial[blockIdx.x] = sm[0] + sm[1] + sm[2] + sm[3];
}
__global__ void scan2(int* __restrict__ partial, int P) {
    if (blockIdx.x == 0 && threadIdx.x == 0) {
        int run = 0;
        for (int i = 0; i < P; ++i) { int v = partial[i]; partial[i] = run; run += v; }
    }
}
__global__ void scan3(const int* __restrict__ deg, const int* __restrict__ partial,
                      int* __restrict__ row, int N, int E) {
    int t = threadIdx.x;
    int lane = t & 63, wv = t >> 6;
    int base = blockIdx.x * 1024 + t * 4;
    int d[4]; int s = 0;
    #pragma unroll
    for (int i = 0; i < 4; ++i) { int idx = base + i; d[i] = (idx < N) ? deg[idx] : 0; s += d[i]; }
    int inc = s;
    #pragma unroll
    for (int off = 1; off < 64; off <<= 1) { int v = __shfl_up(inc, off); if (lane >= off) inc += v; }
    __shared__ int wsum[4];
    if (lane == 63) wsum[wv] = inc;
    __syncthreads();
    int woff = 0;
    for (int w = 0; w < wv; ++w) woff += wsum[w];
    int run = inc - s + woff + partial[blockIdx.x];
    #pragma unroll
    for (int i = 0; i < 4; ++i) { int idx = base + i; if (idx < N) row[idx] = run; run += d[i]; }
    if (blockIdx.x == 0 && t == 0) row[N] = E;
}
__global__ __launch_bounds__(256)
void fill_adj_ranged(const int* __restrict__ src, const int* __restrict__ dst,
                     int* __restrict__ cur_h, int* __restrict__ cur_b,
                     int* __restrict__ adj_h, int* __restrict__ adj_b,
                     int E, int N, int nch) {
    const int NR = 8;
    int r     = blockIdx.x & (NR - 1);
    int chunk = blockIdx.x >> 3;
    int rng = (N + NR - 1) / NR;
    int lo = r * rng;
    int hi = lo + rng; if (hi > N) hi = N;
    int per = (E + nch - 1) / nch;
    int e0 = chunk * per;
    int e1 = e0 + per; if (e1 > E) e1 = E;
    for (int e = e0 + (int)threadIdx.x; e < e1; e += 256) {
        int s = __builtin_nontemporal_load(src + e);
        int d = __builtin_nontemporal_load(dst + e);
        if (s >= lo && s < hi) adj_h[atomicAdd(cur_h + s, 1)] = d;
        if (d >= lo && d < hi) adj_b[atomicAdd(cur_b + d, 1)] = s;
    }
}

// ---------- f32 -> bf16 elementwise convert ----------
__global__ void cvt_to_bf16(const float* __restrict__ in, unsigned short* __restrict__ out,
                            size_t n4) {
    size_t t = (size_t)blockIdx.x * blockDim.x + threadIdx.x;
    if (t >= n4) return;
    const float4 v = *(const float4*)(in + t * 4);
    ushort4 u;
    u.x = f2b(v.x); u.y = f2b(v.y); u.z = f2b(v.z); u.w = f2b(v.w);
    *(ushort4*)(out + t * 4) = u;
}

// ---------- gather + mean + bf16 out (ELL or CSR via ell flag) ----------
// One wave per node; G row-groups of LPR lanes at 16B/lane; UNR-deep pipeline.
template <int D>
__global__ __launch_bounds__(256)
void gather_mean(const unsigned short* __restrict__ x, const int* __restrict__ rowc,
                 const int* __restrict__ adj, unsigned short* __restrict__ out,
                 int N, int ell) {
    constexpr int LPR = D / 8;        // lanes per row
    constexpr int G   = 64 / LPR;     // rows in parallel per instr
    constexpr int UNR = 16 / G;       // rows in flight = 16
    int wid  = (blockIdx.x * blockDim.x + threadIdx.x) >> 6;
    int lane = threadIdx.x & 63;
    if (wid >= N) return;
    int beg, deg;
    if (ell) { beg = wid << 6; int c = rowc[wid]; deg = (c < 64) ? c : 64; }
    else     { beg = rowc[wid]; deg = rowc[wid + 1] - beg; }

    const int g  = lane >> (LPR == 16 ? 4 : 5);
    const int gl = lane & (LPR - 1);

    float acc[8];
    #pragma unroll
    for (int p = 0; p < 8; ++p) acc[p] = 0.0f;

    for (int base = 0; base < deg; base += 64) {
        int nb_l = (base + lane < deg) ? adj[beg + base + lane] : 0;
        int m = deg - base; if (m > 64) m = 64;
        int j = 0;
        for (; j + UNR * G <= m; j += UNR * G) {
            int nn[UNR];
            #pragma unroll
            for (int u = 0; u < UNR; ++u) nn[u] = __shfl(nb_l, j + u * G + g);
            short8 vv[UNR];
            #pragma unroll
            for (int u = 0; u < UNR; ++u)
                vv[u] = *(const short8*)(x + (size_t)nn[u] * D + gl * 8);
            #pragma unroll
            for (int u = 0; u < UNR; ++u)
                #pragma unroll
                for (int p = 0; p < 8; ++p) acc[p] += b2f((unsigned short)vv[u][p]);
        }
        for (; j < m; j += G) {
            int idx = j + g;
            int nb = __shfl(nb_l, idx);
            if (idx < m) {
                const short8 v = *(const short8*)(x + (size_t)nb * D + gl * 8);
                #pragma unroll
                for (int p = 0; p < 8; ++p) acc[p] += b2f((unsigned short)v[p]);
            }
        }
    }
    #pragma unroll
    for (int off = LPR; off < 64; off <<= 1) {
        #pragma unroll
        for (int p = 0; p < 8; ++p) acc[p] += __shfl_xor(acc[p], off);
    }
    float inv = 1.0f / (float)((deg > 0) ? deg : 1);
    if (lane < LPR) {
        unsigned short* op = out + (size_t)wid * D + lane * 8;
        short8 u;
        #pragma unroll
        for (int p = 0; p < 8; ++p) u[p] = (short)f2b(acc[p] * inv);
        *(short8*)op = u;
    }
}

// ---------- 4-matrix weight transpose: W f32 [K][256] -> Wt bf16 [256][K] ----------
__global__ void transpose_w4(const float* __restrict__ W0, const float* __restrict__ W1,
                             const float* __restrict__ W2, const float* __restrict__ W3,
                             unsigned short* __restrict__ T0, unsigned short* __restrict__ T1,
                             unsigned short* __restrict__ T2, unsigned short* __restrict__ T3,
                             int K) {
    int k = blockIdx.x;        // [0,K)
    int c = threadIdx.x;       // [0,256)
    int m = blockIdx.y;
    const float* W = (m == 0) ? W0 : (m == 1) ? W1 : (m == 2) ? W2 : W3;
    unsigned short* T = (m == 0) ? T0 : (m == 1) ? T1 : (m == 2) ? T2 : T3;
    T[(size_t)c * K + k] = f2b(W[(size_t)k * 256 + c]);
}

// ---------- fused GEMM: res = relu(A0@B0^T + A1@B1^T + bias) ----------
// Tile 128x256, BK=64, 8 waves (512 thr): per-wave 64x64 (acc[4][4], proven
// shape), 32 MFMA per 6 gload per chunk (1.67x density vs 64x256 tile).
template <bool F32OUT>
__global__ __launch_bounds__(512, 2)
void gemm_fused(const unsigned short* __restrict__ A0, const unsigned short* __restrict__ A1,
                const unsigned short* __restrict__ B0, const unsigned short* __restrict__ B1,
                const float* __restrict__ bias,
                float* __restrict__ outf, unsigned short* __restrict__ outb,
                int M, int K) {
    __shared__ unsigned short As[128 * 64];   // 16 KB
    __shared__ unsigned short Bs[256 * 64];   // 32 KB
    const int tid  = threadIdx.x;
    const int wave = tid >> 6, lane = tid & 63;
    const int wm   = wave >> 2;               // 0..1
    const int wn   = wave & 3;                // 0..3
    const int row0 = blockIdx.x * 128;

    float4v acc[4][4];
    #pragma unroll
    for (int i = 0; i < 4; ++i)
        #pragma unroll
        for (int j = 0; j < 4; ++j) acc[i][j] = (float4v){0.f, 0.f, 0.f, 0.f};

    const int r  = lane >> 3;
    const int cg = lane & 7;
    const int kchunks = K >> 6;
    const int nchunks = kchunks * 2;

    for (int c = 0; c < nchunks; ++c) {
        const unsigned short* Aseg = (c < kchunks) ? A0 : A1;
        const unsigned short* Bseg = (c < kchunks) ? B0 : B1;
        const int k0 = ((c < kchunks) ? c : c - kchunks) << 6;

        if (c) __syncthreads();
        {   // stage A: 128 rows; 16 rows per wave
            int rr = wave * 16;
            const unsigned short* gp = Aseg + (size_t)(row0 + rr + r) * K + k0 + cg * 8;
            unsigned short* lp = As + rr * 64;
            if (row0 + rr + r < M)     gload_lds16(gp, lp);
            if (row0 + rr + 8 + r < M) gload_lds16(gp + 8 * (size_t)K, lp + 8 * 64);
        }
        {   // stage B: 256 rows; 32 rows per wave
            int rr = wave * 32;
            const unsigned short* gp = Bseg + (size_t)(rr + r) * K + k0 + cg * 8;
            unsigned short* lp = Bs + rr * 64;
            #pragma unroll
            for (int i = 0; i < 4; ++i)
                gload_lds16(gp + (size_t)(i * 8) * K, lp + i * 8 * 64);
        }
        __syncthreads();

        const int q8 = (lane >> 4) * 8;
        const int l15 = lane & 15;
        #pragma unroll
        for (int kk = 0; kk <= 32; kk += 32) {
            short8 af[4], bf[4];
            #pragma unroll
            for (int f = 0; f < 4; ++f)
                af[f] = *(const short8*)(As + (wm * 64 + f * 16 + l15) * 64 + kk + q8);
            #pragma unroll
            for (int f = 0; f < 4; ++f)
                bf[f] = *(const short8*)(Bs + (wn * 64 + f * 16 + l15) * 64 + kk + q8);
            #pragma unroll
            for (int fm = 0; fm < 4; ++fm)
                #pragma unroll
                for (int fn = 0; fn < 4; ++fn)
                    acc[fm][fn] = __builtin_amdgcn_mfma_f32_16x16x32_bf16(
                        af[fm], bf[fn], acc[fm][fn], 0, 0, 0);
        }
    }

    // epilogue: C/D layout col=lane&15, row=(lane>>4)*4+reg  [verified m89/m91]
    const int l15 = lane & 15;
    const int rq  = (lane >> 4) * 4;
    #pragma unroll
    for (int fn = 0; fn < 4; ++fn) {
        int col = wn * 64 + fn * 16 + l15;
        float bv = bias[col];
        #pragma unroll
        for (int fm = 0; fm < 4; ++fm) {
            #pragma unroll
            for (int rg = 0; rg < 4; ++rg) {
                int row = row0 + wm * 64 + fm * 16 + rq + rg;
                if (row < M) {
                    float v = fmaxf(acc[fm][fn][rg] + bv, 0.0f);
                    if (F32OUT) outf[(size_t)row * 256 + col] = v;
                    else        outb[(size_t)row * 256 + col] = f2b(v);
                }
            }
        }
    }
}

// ---------- launcher ----------
extern "C" void kernel_launch(void* const* d_in, const int* in_sizes, int n_in,
                              void* d_out, int out_size, void* d_ws, size_t ws_size,
                              hipStream_t stream) {
    const int DIN = 128, H = 256;
    const int N = in_sizes[0] / DIN;
    const int E = in_sizes[2] / 2;

    const float* xh = (const float*)d_in[0];
    const float* xb = (const float*)d_in[1];
    const int* ei  = (const int*)d_in[2];
    const int* src = ei;
    const int* dst = ei + E;
    const float* h1Wl = (const float*)d_in[3];
    const float* h1Wr = (const float*)d_in[4];
    const float* h1b  = (const float*)d_in[5];
    const float* h2Wl = (const float*)d_in[6];
    const float* h2Wr = (const float*)d_in[7];
    const float* h2b  = (const float*)d_in[8];
    const float* b1Wl = (const float*)d_in[9];
    const float* b1Wr = (const float*)d_in[10];
    const float* b1b  = (const float*)d_in[11];
    const float* b2Wl = (const float*)d_in[12];
    const float* b2Wr = (const float*)d_in[13];
    const float* b2b  = (const float*)d_in[14];

    float* outH = (float*)d_out;
    float* outB = outH + (size_t)N * H;

    const int BLK = 256;
    dim3 blk(BLK);

    // bf16 tail: weights + xbf + aggbf + hbf
    const size_t bfElems = (size_t)4 * DIN * H + (size_t)4 * H * H
                         + (size_t)N * DIN + (size_t)2 * N * H;
    const size_t bfBytes = bfElems * 2 + 64;

    // ELL needs: cnt 2N + adj 2*64*N ints
    const size_t needELL = ((size_t)2 * N + (size_t)128 * N) * 4 + bfBytes;
    const bool useELL = ws_size >= needELL;

    const int* rc_h; const int* rc_b; const int* ajh; const int* ajb;
    uintptr_t intEnd;

    if (useELL) {
        int* cnt_h = (int*)d_ws;
        int* cnt_b = cnt_h + N;
        int* adj_h = cnt_b + N;
        int* adj_b = adj_h + (size_t)N * 64;
        intEnd = (uintptr_t)(adj_b + (size_t)N * 64);

        hipMemsetAsync(cnt_h, 0, (size_t)2 * N * sizeof(int), stream);
        const int NCH = 256;
        fill_ell_dir<<<dim3(NCH * 8), blk, 0, stream>>>(src, dst, cnt_h, adj_h, E, N, NCH);
        fill_ell_dir<<<dim3(NCH * 8), blk, 0, stream>>>(dst, src, cnt_b, adj_b, E, N, NCH);
        rc_h = cnt_h; rc_b = cnt_b; ajh = adj_h; ajb = adj_b;
    } else {
        int* deg_h = (int*)d_ws;
        int* deg_b = deg_h + N;
        int* row_h = deg_b + N;
        int* row_b = row_h + (N + 1);
        int* cur_h = row_b + (N + 1);
        int* cur_b = cur_h + N;
        int* partial = cur_b + N;
        int* adj_h = partial + 256;
        int* adj_b = adj_h + E;
        intEnd = (uintptr_t)(adj_b + E);

        const int P = (N + 1023) / 1024;
        hipMemsetAsync(deg_h, 0, (size_t)2 * N * sizeof(int), stream);
        count_deg<<<dim3((E + BLK - 1) / BLK), blk, 0, stream>>>(src, dst, deg_h, deg_b, E);
        scan1<<<dim3(P), blk, 0, stream>>>(deg_h, partial, N);
        scan2<<<dim3(1), blk, 0, stream>>>(partial, P);
        scan3<<<dim3(P), blk, 0, stream>>>(deg_h, partial, row_h, N, E);
        scan1<<<dim3(P), blk, 0, stream>>>(deg_b, partial, N);
        scan2<<<dim3(1), blk, 0, stream>>>(partial, P);
        scan3<<<dim3(P), blk, 0, stream>>>(deg_b, partial, row_b, N, E);
        hipMemcpyAsync(cur_h, row_h, (size_t)N * sizeof(int), hipMemcpyDeviceToDevice, stream);
        hipMemcpyAsync(cur_b, row_b, (size_t)N * sizeof(int), hipMemcpyDeviceToDevice, stream);
        const int NCH = 256;
        fill_adj_ranged<<<dim3(NCH * 8), blk, 0, stream>>>(src, dst, cur_h, cur_b,
                                                           adj_h, adj_b, E, N, NCH);
        rc_h = row_h; rc_b = row_b; ajh = adj_h; ajb = adj_b;
    }
    const int ellf = useELL ? 1 : 0;

    // bf16 region (64B aligned)
    uintptr_t up = (intEnd + 63) & ~(uintptr_t)63;
    unsigned short* wtp = (unsigned short*)up;
    unsigned short* t_h1l = wtp; wtp += DIN * H;
    unsigned short* t_h1r = wtp; wtp += DIN * H;
    unsigned short* t_h2l = wtp; wtp += H * H;
    unsigned short* t_h2r = wtp; wtp += H * H;
    unsigned short* t_b1l = wtp; wtp += DIN * H;
    unsigned short* t_b1r = wtp; wtp += DIN * H;
    unsigned short* t_b2l = wtp; wtp += H * H;
    unsigned short* t_b2r = wtp; wtp += H * H;
    unsigned short* xbf   = wtp;
    unsigned short* aggbf = xbf + (size_t)N * DIN;
    unsigned short* hbf   = aggbf + (size_t)N * H;

    // weight transposes: 2 launches (K=128 quad, K=256 quad)
    transpose_w4<<<dim3(DIN, 4), blk, 0, stream>>>(h1Wl, h1Wr, b1Wl, b1Wr,
                                                   t_h1l, t_h1r, t_b1l, t_b1r, DIN);
    transpose_w4<<<dim3(H, 4),   blk, 0, stream>>>(h2Wl, h2Wr, b2Wl, b2Wr,
                                                   t_h2l, t_h2r, t_b2l, t_b2r, H);

    dim3 nggrid((N + 3) / 4);
    dim3 ggrid((N + 127) / 128);
    dim3 gblk(512);
    int ncvt = ((size_t)N * DIN / 4 + BLK - 1) / BLK;

    // ---- human branch ----
    cvt_to_bf16<<<dim3(ncvt), blk, 0, stream>>>(xh, xbf, (size_t)N * DIN / 4);
    gather_mean<128><<<nggrid, blk, 0, stream>>>(xbf, rc_h, ajh, aggbf, N, ellf);
    gemm_fused<false><<<ggrid, gblk, 0, stream>>>(aggbf, xbf, t_h1l, t_h1r, h1b,
                                                  nullptr, hbf, N, DIN);
    gather_mean<256><<<nggrid, blk, 0, stream>>>(hbf, rc_h, ajh, aggbf, N, ellf);
    gemm_fused<true><<<ggrid, gblk, 0, stream>>>(aggbf, hbf, t_h2l, t_h2r, h2b,
                                                 outH, nullptr, N, H);

    // ---- bacterial branch ----
    cvt_to_bf16<<<dim3(ncvt), blk, 0, stream>>>(xb, xbf, (size_t)N * DIN / 4);
    gather_mean<128><<<nggrid, blk, 0, stream>>>(xbf, rc_b, ajb, aggbf, N, ellf);
    gemm_fused<false><<<ggrid, gblk, 0, stream>>>(aggbf, xbf, t_b1l, t_b1r, b1b,
                                                  nullptr, hbf, N, DIN);
    gather_mean<256><<<nggrid, blk, 0, stream>>>(hbf, rc_b, ajb, aggbf, N, ellf);
    gemm_fused<true><<<ggrid, gblk, 0, stream>>>(aggbf, hbf, t_b2l, t_b2r, b2b,
                                                 outB, nullptr, N, H);
}

// Round 7
// 1113.924 us; speedup vs baseline: 1.0042x; 1.0042x over previous
//
#include <hip/hip_runtime.h>
#include <stdint.h>

// ---------- types / helpers ----------
using short8  = __attribute__((ext_vector_type(8))) short;
using float4v = __attribute__((ext_vector_type(4))) float;

__device__ __forceinline__ float b2f(unsigned short u) {
    union { unsigned int i; float f; } v; v.i = ((unsigned int)u) << 16; return v.f;
}
__device__ __forceinline__ unsigned short f2b(float f) {
    union { float f; unsigned int i; } v; v.f = f;
    unsigned int x = v.i;
    unsigned int r = (x + 0x7fffu + ((x >> 16) & 1u)) >> 16;   // RNE
    return (unsigned short)r;
}

__device__ __forceinline__ void gload_lds16(const void* g, void* l) {
    __builtin_amdgcn_global_load_lds((const __attribute__((address_space(1))) void*)g,
                                     (__attribute__((address_space(3))) void*)l, 16, 0, 0);
}

// ================= ELL fill (primary; combined directions, R5-proven) =================
// Both directions in one pass: two independent atomic/store chains per edge
// give per-thread MLP (R6 lesson: splitting directions cost ~+75us).
__global__ __launch_bounds__(256)
void fill_ell_ranged(const int* __restrict__ src, const int* __restrict__ dst,
                     int* __restrict__ cnt_h, int* __restrict__ cnt_b,
                     int* __restrict__ adj_h, int* __restrict__ adj_b,
                     int E, int N, int nch) {
    const int NR = 8;
    int r     = blockIdx.x & (NR - 1);
    int chunk = blockIdx.x >> 3;
    int rng = (N + NR - 1) / NR;
    int lo = r * rng;
    int hi = lo + rng; if (hi > N) hi = N;
    int per = (E + nch - 1) / nch;
    int e0 = chunk * per;
    int e1 = e0 + per; if (e1 > E) e1 = E;
    for (int e = e0 + (int)threadIdx.x; e < e1; e += 256) {
        int s = __builtin_nontemporal_load(src + e);
        int d = __builtin_nontemporal_load(dst + e);
        if (s >= lo && s < hi) {
            int sl = atomicAdd(cnt_h + s, 1);
            if (sl < 64) adj_h[((size_t)s << 6) + sl] = d;
        }
        if (d >= lo && d < hi) {
            int sl = atomicAdd(cnt_b + d, 1);
            if (sl < 64) adj_b[((size_t)d << 6) + sl] = s;
        }
    }
}

// ================= CSR fallback path (if ws too small for ELL) =================
__global__ void count_deg(const int* __restrict__ src, const int* __restrict__ dst,
                          int* __restrict__ deg_h, int* __restrict__ deg_b, int E) {
    int e = blockIdx.x * blockDim.x + threadIdx.x;
    if (e < E) {
        int s = __builtin_nontemporal_load(src + e);
        int d = __builtin_nontemporal_load(dst + e);
        atomicAdd(deg_h + s, 1);
        atomicAdd(deg_b + d, 1);
    }
}
__global__ void scan1(const int* __restrict__ deg, int* __restrict__ partial, int N) {
    int t = threadIdx.x;
    int base = blockIdx.x * 1024 + t * 4;
    int s = 0;
    #pragma unroll
    for (int i = 0; i < 4; ++i) { int idx = base + i; if (idx < N) s += deg[idx]; }
    #pragma unroll
    for (int off = 32; off; off >>= 1) s += __shfl_down(s, off);
    __shared__ int sm[4];
    if ((t & 63) == 0) sm[t >> 6] = s;
    __syncthreads();
    if (t == 0) partial[blockIdx.x] = sm[0] + sm[1] + sm[2] + sm[3];
}
__global__ void scan2(int* __restrict__ partial, int P) {
    if (blockIdx.x == 0 && threadIdx.x == 0) {
        int run = 0;
        for (int i = 0; i < P; ++i) { int v = partial[i]; partial[i] = run; run += v; }
    }
}
__global__ void scan3(const int* __restrict__ deg, const int* __restrict__ partial,
                      int* __restrict__ row, int N, int E) {
    int t = threadIdx.x;
    int lane = t & 63, wv = t >> 6;
    int base = blockIdx.x * 1024 + t * 4;
    int d[4]; int s = 0;
    #pragma unroll
    for (int i = 0; i < 4; ++i) { int idx = base + i; d[i] = (idx < N) ? deg[idx] : 0; s += d[i]; }
    int inc = s;
    #pragma unroll
    for (int off = 1; off < 64; off <<= 1) { int v = __shfl_up(inc, off); if (lane >= off) inc += v; }
    __shared__ int wsum[4];
    if (lane == 63) wsum[wv] = inc;
    __syncthreads();
    int woff = 0;
    for (int w = 0; w < wv; ++w) woff += wsum[w];
    int run = inc - s + woff + partial[blockIdx.x];
    #pragma unroll
    for (int i = 0; i < 4; ++i) { int idx = base + i; if (idx < N) row[idx] = run; run += d[i]; }
    if (blockIdx.x == 0 && t == 0) row[N] = E;
}
__global__ __launch_bounds__(256)
void fill_adj_ranged(const int* __restrict__ src, const int* __restrict__ dst,
                     int* __restrict__ cur_h, int* __restrict__ cur_b,
                     int* __restrict__ adj_h, int* __restrict__ adj_b,
                     int E, int N, int nch) {
    const int NR = 8;
    int r     = blockIdx.x & (NR - 1);
    int chunk = blockIdx.x >> 3;
    int rng = (N + NR - 1) / NR;
    int lo = r * rng;
    int hi = lo + rng; if (hi > N) hi = N;
    int per = (E + nch - 1) / nch;
    int e0 = chunk * per;
    int e1 = e0 + per; if (e1 > E) e1 = E;
    for (int e = e0 + (int)threadIdx.x; e < e1; e += 256) {
        int s = __builtin_nontemporal_load(src + e);
        int d = __builtin_nontemporal_load(dst + e);
        if (s >= lo && s < hi) adj_h[atomicAdd(cur_h + s, 1)] = d;
        if (d >= lo && d < hi) adj_b[atomicAdd(cur_b + d, 1)] = s;
    }
}

// ---------- f32 -> bf16 elementwise convert ----------
__global__ void cvt_to_bf16(const float* __restrict__ in, unsigned short* __restrict__ out,
                            size_t n4) {
    size_t t = (size_t)blockIdx.x * blockDim.x + threadIdx.x;
    if (t >= n4) return;
    const float4 v = *(const float4*)(in + t * 4);
    ushort4 u;
    u.x = f2b(v.x); u.y = f2b(v.y); u.z = f2b(v.z); u.w = f2b(v.w);
    *(ushort4*)(out + t * 4) = u;
}

// ---------- gather + mean + bf16 out (ELL or CSR via ell flag) ----------
// One wave per node; G row-groups of LPR lanes at 16B/lane; UNR-deep pipeline.
template <int D>
__global__ __launch_bounds__(256)
void gather_mean(const unsigned short* __restrict__ x, const int* __restrict__ rowc,
                 const int* __restrict__ adj, unsigned short* __restrict__ out,
                 int N, int ell) {
    constexpr int LPR = D / 8;        // lanes per row
    constexpr int G   = 64 / LPR;     // rows in parallel per instr
    constexpr int UNR = 16 / G;       // rows in flight = 16
    int wid  = (blockIdx.x * blockDim.x + threadIdx.x) >> 6;
    int lane = threadIdx.x & 63;
    if (wid >= N) return;
    int beg, deg;
    if (ell) { beg = wid << 6; int c = rowc[wid]; deg = (c < 64) ? c : 64; }
    else     { beg = rowc[wid]; deg = rowc[wid + 1] - beg; }

    const int g  = lane >> (LPR == 16 ? 4 : 5);
    const int gl = lane & (LPR - 1);

    float acc[8];
    #pragma unroll
    for (int p = 0; p < 8; ++p) acc[p] = 0.0f;

    for (int base = 0; base < deg; base += 64) {
        int nb_l = (base + lane < deg) ? adj[beg + base + lane] : 0;
        int m = deg - base; if (m > 64) m = 64;
        int j = 0;
        for (; j + UNR * G <= m; j += UNR * G) {
            int nn[UNR];
            #pragma unroll
            for (int u = 0; u < UNR; ++u) nn[u] = __shfl(nb_l, j + u * G + g);
            short8 vv[UNR];
            #pragma unroll
            for (int u = 0; u < UNR; ++u)
                vv[u] = *(const short8*)(x + (size_t)nn[u] * D + gl * 8);
            #pragma unroll
            for (int u = 0; u < UNR; ++u)
                #pragma unroll
                for (int p = 0; p < 8; ++p) acc[p] += b2f((unsigned short)vv[u][p]);
        }
        for (; j < m; j += G) {
            int idx = j + g;
            int nb = __shfl(nb_l, idx);
            if (idx < m) {
                const short8 v = *(const short8*)(x + (size_t)nb * D + gl * 8);
                #pragma unroll
                for (int p = 0; p < 8; ++p) acc[p] += b2f((unsigned short)v[p]);
            }
        }
    }
    #pragma unroll
    for (int off = LPR; off < 64; off <<= 1) {
        #pragma unroll
        for (int p = 0; p < 8; ++p) acc[p] += __shfl_xor(acc[p], off);
    }
    float inv = 1.0f / (float)((deg > 0) ? deg : 1);
    if (lane < LPR) {
        unsigned short* op = out + (size_t)wid * D + lane * 8;
        short8 u;
        #pragma unroll
        for (int p = 0; p < 8; ++p) u[p] = (short)f2b(acc[p] * inv);
        *(short8*)op = u;
    }
}

// ---------- 4-matrix weight transpose: W f32 [K][256] -> Wt bf16 [256][K] ----------
__global__ void transpose_w4(const float* __restrict__ W0, const float* __restrict__ W1,
                             const float* __restrict__ W2, const float* __restrict__ W3,
                             unsigned short* __restrict__ T0, unsigned short* __restrict__ T1,
                             unsigned short* __restrict__ T2, unsigned short* __restrict__ T3,
                             int K) {
    int k = blockIdx.x;        // [0,K)
    int c = threadIdx.x;       // [0,256)
    int m = blockIdx.y;
    const float* W = (m == 0) ? W0 : (m == 1) ? W1 : (m == 2) ? W2 : W3;
    unsigned short* T = (m == 0) ? T0 : (m == 1) ? T1 : (m == 2) ? T2 : T3;
    T[(size_t)c * K + k] = f2b(W[(size_t)k * 256 + c]);
}

// ---------- fused GEMM: res = relu(A0@B0^T + A1@B1^T + bias) ----------
// Tile 128x256, BK=64, 8 waves (512 thr): per-wave 64x64 (acc[4][4], proven
// shape), 32 MFMA per 6 gload per chunk (1.67x density vs 64x256 tile).
template <bool F32OUT>
__global__ __launch_bounds__(512, 2)
void gemm_fused(const unsigned short* __restrict__ A0, const unsigned short* __restrict__ A1,
                const unsigned short* __restrict__ B0, const unsigned short* __restrict__ B1,
                const float* __restrict__ bias,
                float* __restrict__ outf, unsigned short* __restrict__ outb,
                int M, int K) {
    __shared__ unsigned short As[128 * 64];   // 16 KB
    __shared__ unsigned short Bs[256 * 64];   // 32 KB
    const int tid  = threadIdx.x;
    const int wave = tid >> 6, lane = tid & 63;
    const int wm   = wave >> 2;               // 0..1
    const int wn   = wave & 3;                // 0..3
    const int row0 = blockIdx.x * 128;

    float4v acc[4][4];
    #pragma unroll
    for (int i = 0; i < 4; ++i)
        #pragma unroll
        for (int j = 0; j < 4; ++j) acc[i][j] = (float4v){0.f, 0.f, 0.f, 0.f};

    const int r  = lane >> 3;
    const int cg = lane & 7;
    const int kchunks = K >> 6;
    const int nchunks = kchunks * 2;

    for (int c = 0; c < nchunks; ++c) {
        const unsigned short* Aseg = (c < kchunks) ? A0 : A1;
        const unsigned short* Bseg = (c < kchunks) ? B0 : B1;
        const int k0 = ((c < kchunks) ? c : c - kchunks) << 6;

        if (c) __syncthreads();
        {   // stage A: 128 rows; 16 rows per wave
            int rr = wave * 16;
            const unsigned short* gp = Aseg + (size_t)(row0 + rr + r) * K + k0 + cg * 8;
            unsigned short* lp = As + rr * 64;
            if (row0 + rr + r < M)     gload_lds16(gp, lp);
            if (row0 + rr + 8 + r < M) gload_lds16(gp + 8 * (size_t)K, lp + 8 * 64);
        }
        {   // stage B: 256 rows; 32 rows per wave
            int rr = wave * 32;
            const unsigned short* gp = Bseg + (size_t)(rr + r) * K + k0 + cg * 8;
            unsigned short* lp = Bs + rr * 64;
            #pragma unroll
            for (int i = 0; i < 4; ++i)
                gload_lds16(gp + (size_t)(i * 8) * K, lp + i * 8 * 64);
        }
        __syncthreads();

        const int q8 = (lane >> 4) * 8;
        const int l15 = lane & 15;
        #pragma unroll
        for (int kk = 0; kk <= 32; kk += 32) {
            short8 af[4], bf[4];
            #pragma unroll
            for (int f = 0; f < 4; ++f)
                af[f] = *(const short8*)(As + (wm * 64 + f * 16 + l15) * 64 + kk + q8);
            #pragma unroll
            for (int f = 0; f < 4; ++f)
                bf[f] = *(const short8*)(Bs + (wn * 64 + f * 16 + l15) * 64 + kk + q8);
            #pragma unroll
            for (int fm = 0; fm < 4; ++fm)
                #pragma unroll
                for (int fn = 0; fn < 4; ++fn)
                    acc[fm][fn] = __builtin_amdgcn_mfma_f32_16x16x32_bf16(
                        af[fm], bf[fn], acc[fm][fn], 0, 0, 0);
        }
    }

    // epilogue: C/D layout col=lane&15, row=(lane>>4)*4+reg  [verified m89/m91]
    const int l15 = lane & 15;
    const int rq  = (lane >> 4) * 4;
    #pragma unroll
    for (int fn = 0; fn < 4; ++fn) {
        int col = wn * 64 + fn * 16 + l15;
        float bv = bias[col];
        #pragma unroll
        for (int fm = 0; fm < 4; ++fm) {
            #pragma unroll
            for (int rg = 0; rg < 4; ++rg) {
                int row = row0 + wm * 64 + fm * 16 + rq + rg;
                if (row < M) {
                    float v = fmaxf(acc[fm][fn][rg] + bv, 0.0f);
                    if (F32OUT) outf[(size_t)row * 256 + col] = v;
                    else        outb[(size_t)row * 256 + col] = f2b(v);
                }
            }
        }
    }
}

// ---------- launcher ----------
extern "C" void kernel_launch(void* const* d_in, const int* in_sizes, int n_in,
                              void* d_out, int out_size, void* d_ws, size_t ws_size,
                              hipStream_t stream) {
    const int DIN = 128, H = 256;
    const int N = in_sizes[0] / DIN;
    const int E = in_sizes[2] / 2;

    const float* xh = (const float*)d_in[0];
    const float* xb = (const float*)d_in[1];
    const int* ei  = (const int*)d_in[2];
    const int* src = ei;
    const int* dst = ei + E;
    const float* h1Wl = (const float*)d_in[3];
    const float* h1Wr = (const float*)d_in[4];
    const float* h1b  = (const float*)d_in[5];
    const float* h2Wl = (const float*)d_in[6];
    const float* h2Wr = (const float*)d_in[7];
    const float* h2b  = (const float*)d_in[8];
    const float* b1Wl = (const float*)d_in[9];
    const float* b1Wr = (const float*)d_in[10];
    const float* b1b  = (const float*)d_in[11];
    const float* b2Wl = (const float*)d_in[12];
    const float* b2Wr = (const float*)d_in[13];
    const float* b2b  = (const float*)d_in[14];

    float* outH = (float*)d_out;
    float* outB = outH + (size_t)N * H;

    const int BLK = 256;
    dim3 blk(BLK);

    // bf16 tail: weights + xbf + aggbf + hbf
    const size_t bfElems = (size_t)4 * DIN * H + (size_t)4 * H * H
                         + (size_t)N * DIN + (size_t)2 * N * H;
    const size_t bfBytes = bfElems * 2 + 64;

    // ELL needs: cnt 2N + adj 2*64*N ints
    const size_t needELL = ((size_t)2 * N + (size_t)128 * N) * 4 + bfBytes;
    const bool useELL = ws_size >= needELL;

    const int* rc_h; const int* rc_b; const int* ajh; const int* ajb;
    uintptr_t intEnd;

    if (useELL) {
        int* cnt_h = (int*)d_ws;
        int* cnt_b = cnt_h + N;
        int* adj_h = cnt_b + N;
        int* adj_b = adj_h + (size_t)N * 64;
        intEnd = (uintptr_t)(adj_b + (size_t)N * 64);

        hipMemsetAsync(cnt_h, 0, (size_t)2 * N * sizeof(int), stream);
        const int NCH = 256;
        fill_ell_ranged<<<dim3(NCH * 8), blk, 0, stream>>>(src, dst, cnt_h, cnt_b,
                                                           adj_h, adj_b, E, N, NCH);
        rc_h = cnt_h; rc_b = cnt_b; ajh = adj_h; ajb = adj_b;
    } else {
        int* deg_h = (int*)d_ws;
        int* deg_b = deg_h + N;
        int* row_h = deg_b + N;
        int* row_b = row_h + (N + 1);
        int* cur_h = row_b + (N + 1);
        int* cur_b = cur_h + N;
        int* partial = cur_b + N;
        int* adj_h = partial + 256;
        int* adj_b = adj_h + E;
        intEnd = (uintptr_t)(adj_b + E);

        const int P = (N + 1023) / 1024;
        hipMemsetAsync(deg_h, 0, (size_t)2 * N * sizeof(int), stream);
        count_deg<<<dim3((E + BLK - 1) / BLK), blk, 0, stream>>>(src, dst, deg_h, deg_b, E);
        scan1<<<dim3(P), blk, 0, stream>>>(deg_h, partial, N);
        scan2<<<dim3(1), blk, 0, stream>>>(partial, P);
        scan3<<<dim3(P), blk, 0, stream>>>(deg_h, partial, row_h, N, E);
        scan1<<<dim3(P), blk, 0, stream>>>(deg_b, partial, N);
        scan2<<<dim3(1), blk, 0, stream>>>(partial, P);
        scan3<<<dim3(P), blk, 0, stream>>>(deg_b, partial, row_b, N, E);
        hipMemcpyAsync(cur_h, row_h, (size_t)N * sizeof(int), hipMemcpyDeviceToDevice, stream);
        hipMemcpyAsync(cur_b, row_b, (size_t)N * sizeof(int), hipMemcpyDeviceToDevice, stream);
        const int NCH = 256;
        fill_adj_ranged<<<dim3(NCH * 8), blk, 0, stream>>>(src, dst, cur_h, cur_b,
                                                           adj_h, adj_b, E, N, NCH);
        rc_h = row_h; rc_b = row_b; ajh = adj_h; ajb = adj_b;
    }
    const int ellf = useELL ? 1 : 0;

    // bf16 region (64B aligned)
    uintptr_t up = (intEnd + 63) & ~(uintptr_t)63;
    unsigned short* wtp = (unsigned short*)up;
    unsigned short* t_h1l = wtp; wtp += DIN * H;
    unsigned short* t_h1r = wtp; wtp += DIN * H;
    unsigned short* t_h2l = wtp; wtp += H * H;
    unsigned short* t_h2r = wtp; wtp += H * H;
    unsigned short* t_b1l = wtp; wtp += DIN * H;
    unsigned short* t_b1r = wtp; wtp += DIN * H;
    unsigned short* t_b2l = wtp; wtp += H * H;
    unsigned short* t_b2r = wtp; wtp += H * H;
    unsigned short* xbf   = wtp;
    unsigned short* aggbf = xbf + (size_t)N * DIN;
    unsigned short* hbf   = aggbf + (size_t)N * H;

    // weight transposes: 2 launches (K=128 quad, K=256 quad)
    transpose_w4<<<dim3(DIN, 4), blk, 0, stream>>>(h1Wl, h1Wr, b1Wl, b1Wr,
                                                   t_h1l, t_h1r, t_b1l, t_b1r, DIN);
    transpose_w4<<<dim3(H, 4),   blk, 0, stream>>>(h2Wl, h2Wr, b2Wl, b2Wr,
                                                   t_h2l, t_h2r, t_b2l, t_b2r, H);

    dim3 nggrid((N + 3) / 4);
    dim3 ggrid((N + 127) / 128);
    dim3 gblk(512);
    int ncvt = ((size_t)N * DIN / 4 + BLK - 1) / BLK;

    // ---- human branch ----
    cvt_to_bf16<<<dim3(ncvt), blk, 0, stream>>>(xh, xbf, (size_t)N * DIN / 4);
    gather_mean<128><<<nggrid, blk, 0, stream>>>(xbf, rc_h, ajh, aggbf, N, ellf);
    gemm_fused<false><<<ggrid, gblk, 0, stream>>>(aggbf, xbf, t_h1l, t_h1r, h1b,
                                                  nullptr, hbf, N, DIN);
    gather_mean<256><<<nggrid, blk, 0, stream>>>(hbf, rc_h, ajh, aggbf, N, ellf);
    gemm_fused<true><<<ggrid, gblk, 0, stream>>>(aggbf, hbf, t_h2l, t_h2r, h2b,
                                                 outH, nullptr, N, H);

    // ---- bacterial branch ----
    cvt_to_bf16<<<dim3(ncvt), blk, 0, stream>>>(xb, xbf, (size_t)N * DIN / 4);
    gather_mean<128><<<nggrid, blk, 0, stream>>>(xbf, rc_b, ajb, aggbf, N, ellf);
    gemm_fused<false><<<ggrid, gblk, 0, stream>>>(aggbf, xbf, t_b1l, t_b1r, b1b,
                                                  nullptr, hbf, N, DIN);
    gather_mean<256><<<nggrid, blk, 0, stream>>>(hbf, rc_b, ajb, aggbf, N, ellf);
    gemm_fused<true><<<ggrid, gblk, 0, stream>>>(aggbf, hbf, t_b2l, t_b2r, b2b,
                                                 outB, nullptr, N, H);
}

// Round 8
// 1037.810 us; speedup vs baseline: 1.0778x; 1.0733x over previous
//
#include <hip/hip_runtime.h>
#include <stdint.h>

// ---------- types / helpers ----------
using short8  = __attribute__((ext_vector_type(8))) short;
using float4v = __attribute__((ext_vector_type(4))) float;

__device__ __forceinline__ float b2f(unsigned short u) {
    union { unsigned int i; float f; } v; v.i = ((unsigned int)u) << 16; return v.f;
}
__device__ __forceinline__ unsigned short f2b(float f) {
    union { float f; unsigned int i; } v; v.f = f;
    unsigned int x = v.i;
    unsigned int r = (x + 0x7fffu + ((x >> 16) & 1u)) >> 16;   // RNE
    return (unsigned short)r;
}

__device__ __forceinline__ void gload_lds16(const void* g, void* l) {
    __builtin_amdgcn_global_load_lds((const __attribute__((address_space(1))) void*)g,
                                     (__attribute__((address_space(3))) void*)l, 16, 0, 0);
}

// ---------- init: pad adj with sentinel N, zero cnt, zero sentinel rows ----------
__global__ __launch_bounds__(256)
void init_ell(int* __restrict__ adj_h, int* __restrict__ adj_b,
              int* __restrict__ cnt, unsigned short* __restrict__ xrow,
              unsigned short* __restrict__ hrow, int N) {
    size_t t = (size_t)blockIdx.x * 256 + threadIdx.x;
    size_t tot4 = (size_t)N * 16;               // N*64 ints / 4 per array
    int4 pv = make_int4(N, N, N, N);
    if (t < tot4) {
        ((int4*)adj_h)[t] = pv;
        ((int4*)adj_b)[t] = pv;
    }
    // zero cnt (2N ints), grid-stride
    size_t nthr = (size_t)gridDim.x * 256;
    for (size_t i = t; i < (size_t)2 * N; i += nthr) cnt[i] = 0;
    // zero sentinel feature rows
    if (blockIdx.x == 0) {
        int i = threadIdx.x;
        if (i < 16) ((short8*)xrow)[i] = (short8)0;   // 128 bf16
        if (i < 32) ((short8*)hrow)[i] = (short8)0;   // 256 bf16
    }
}

// ================= ELL fill (combined directions, R5-proven 147us) =================
__global__ __launch_bounds__(256)
void fill_ell_ranged(const int* __restrict__ src, const int* __restrict__ dst,
                     int* __restrict__ cnt_h, int* __restrict__ cnt_b,
                     int* __restrict__ adj_h, int* __restrict__ adj_b,
                     int E, int N, int nch) {
    const int NR = 8;
    int r     = blockIdx.x & (NR - 1);
    int chunk = blockIdx.x >> 3;
    int rng = (N + NR - 1) / NR;
    int lo = r * rng;
    int hi = lo + rng; if (hi > N) hi = N;
    int per = (E + nch - 1) / nch;
    int e0 = chunk * per;
    int e1 = e0 + per; if (e1 > E) e1 = E;
    for (int e = e0 + (int)threadIdx.x; e < e1; e += 256) {
        int s = __builtin_nontemporal_load(src + e);
        int d = __builtin_nontemporal_load(dst + e);
        if (s >= lo && s < hi) {
            int sl = atomicAdd(cnt_h + s, 1);
            if (sl < 64) adj_h[((size_t)s << 6) + sl] = d;
        }
        if (d >= lo && d < hi) {
            int sl = atomicAdd(cnt_b + d, 1);
            if (sl < 64) adj_b[((size_t)d << 6) + sl] = s;
        }
    }
}

// ================= CSR fallback path (if ws too small for ELL) =================
__global__ void count_deg(const int* __restrict__ src, const int* __restrict__ dst,
                          int* __restrict__ deg_h, int* __restrict__ deg_b, int E) {
    int e = blockIdx.x * blockDim.x + threadIdx.x;
    if (e < E) {
        int s = __builtin_nontemporal_load(src + e);
        int d = __builtin_nontemporal_load(dst + e);
        atomicAdd(deg_h + s, 1);
        atomicAdd(deg_b + d, 1);
    }
}
__global__ void scan1(const int* __restrict__ deg, int* __restrict__ partial, int N) {
    int t = threadIdx.x;
    int base = blockIdx.x * 1024 + t * 4;
    int s = 0;
    #pragma unroll
    for (int i = 0; i < 4; ++i) { int idx = base + i; if (idx < N) s += deg[idx]; }
    #pragma unroll
    for (int off = 32; off; off >>= 1) s += __shfl_down(s, off);
    __shared__ int sm[4];
    if ((t & 63) == 0) sm[t >> 6] = s;
    __syncthreads();
    if (t == 0) partial[blockIdx.x] = sm[0] + sm[1] + sm[2] + sm[3];
}
__global__ void scan2(int* __restrict__ partial, int P) {
    if (blockIdx.x == 0 && threadIdx.x == 0) {
        int run = 0;
        for (int i = 0; i < P; ++i) { int v = partial[i]; partial[i] = run; run += v; }
    }
}
__global__ void scan3(const int* __restrict__ deg, const int* __restrict__ partial,
                      int* __restrict__ row, int N, int E) {
    int t = threadIdx.x;
    int lane = t & 63, wv = t >> 6;
    int base = blockIdx.x * 1024 + t * 4;
    int d[4]; int s = 0;
    #pragma unroll
    for (int i = 0; i < 4; ++i) { int idx = base + i; d[i] = (idx < N) ? deg[idx] : 0; s += d[i]; }
    int inc = s;
    #pragma unroll
    for (int off = 1; off < 64; off <<= 1) { int v = __shfl_up(inc, off); if (lane >= off) inc += v; }
    __shared__ int wsum[4];
    if (lane == 63) wsum[wv] = inc;
    __syncthreads();
    int woff = 0;
    for (int w = 0; w < wv; ++w) woff += wsum[w];
    int run = inc - s + woff + partial[blockIdx.x];
    #pragma unroll
    for (int i = 0; i < 4; ++i) { int idx = base + i; if (idx < N) row[idx] = run; run += d[i]; }
    if (blockIdx.x == 0 && t == 0) row[N] = E;
}
__global__ __launch_bounds__(256)
void fill_adj_ranged(const int* __restrict__ src, const int* __restrict__ dst,
                     int* __restrict__ cur_h, int* __restrict__ cur_b,
                     int* __restrict__ adj_h, int* __restrict__ adj_b,
                     int E, int N, int nch) {
    const int NR = 8;
    int r     = blockIdx.x & (NR - 1);
    int chunk = blockIdx.x >> 3;
    int rng = (N + NR - 1) / NR;
    int lo = r * rng;
    int hi = lo + rng; if (hi > N) hi = N;
    int per = (E + nch - 1) / nch;
    int e0 = chunk * per;
    int e1 = e0 + per; if (e1 > E) e1 = E;
    for (int e = e0 + (int)threadIdx.x; e < e1; e += 256) {
        int s = __builtin_nontemporal_load(src + e);
        int d = __builtin_nontemporal_load(dst + e);
        if (s >= lo && s < hi) adj_h[atomicAdd(cur_h + s, 1)] = d;
        if (d >= lo && d < hi) adj_b[atomicAdd(cur_b + d, 1)] = s;
    }
}

// ---------- f32 -> bf16 elementwise convert ----------
__global__ void cvt_to_bf16(const float* __restrict__ in, unsigned short* __restrict__ out,
                            size_t n4) {
    size_t t = (size_t)blockIdx.x * blockDim.x + threadIdx.x;
    if (t >= n4) return;
    const float4 v = *(const float4*)(in + t * 4);
    ushort4 u;
    u.x = f2b(v.x); u.y = f2b(v.y); u.z = f2b(v.z); u.w = f2b(v.w);
    *(ushort4*)(out + t * 4) = u;
}

// ---------- ELL gather: branch-free (padded slots -> zero row at x[N]) ----------
// One wave per node; G row-groups of LPR lanes at 16B/lane; STEP=16 slots per
// round, unconditional loads (sentinel slots read the L1-hot zero row, add 0).
template <int D>
__global__ __launch_bounds__(256)
void gather_mean_ell(const unsigned short* __restrict__ x, const int* __restrict__ cnt,
                     const int* __restrict__ adj, unsigned short* __restrict__ out, int N) {
    constexpr int LPR = D / 8;
    constexpr int G   = 64 / LPR;
    constexpr int STEP = 16;
    constexpr int UNR = STEP / G;
    int wid  = (blockIdx.x * blockDim.x + threadIdx.x) >> 6;
    int lane = threadIdx.x & 63;
    if (wid >= N) return;
    int c = cnt[wid];
    int deg = (c < 64) ? c : 64;
    int nb_l = __builtin_nontemporal_load(adj + ((size_t)wid << 6) + lane);

    const int g  = lane >> (LPR == 16 ? 4 : 5);
    const int gl = lane & (LPR - 1);

    float acc[8];
    #pragma unroll
    for (int p = 0; p < 8; ++p) acc[p] = 0.0f;

    int rounds = (deg + STEP - 1) / STEP;         // <= 4
    for (int t = 0; t < rounds; ++t) {
        int j = t * STEP;
        int nn[UNR];
        #pragma unroll
        for (int u = 0; u < UNR; ++u) nn[u] = __shfl(nb_l, j + u * G + g);
        short8 vv[UNR];
        #pragma unroll
        for (int u = 0; u < UNR; ++u)
            vv[u] = *(const short8*)(x + (size_t)nn[u] * D + gl * 8);
        #pragma unroll
        for (int u = 0; u < UNR; ++u)
            #pragma unroll
            for (int p = 0; p < 8; ++p) acc[p] += b2f((unsigned short)vv[u][p]);
    }
    #pragma unroll
    for (int off = LPR; off < 64; off <<= 1) {
        #pragma unroll
        for (int p = 0; p < 8; ++p) acc[p] += __shfl_xor(acc[p], off);
    }
    float inv = 1.0f / (float)((deg > 0) ? deg : 1);
    if (lane < LPR) {
        unsigned short* op = out + (size_t)wid * D + lane * 8;
        short8 u;
        #pragma unroll
        for (int p = 0; p < 8; ++p) u[p] = (short)f2b(acc[p] * inv);
        *(short8*)op = u;
    }
}

// ---------- CSR gather (fallback; guarded loop) ----------
template <int D>
__global__ __launch_bounds__(256)
void gather_mean(const unsigned short* __restrict__ x, const int* __restrict__ rowc,
                 const int* __restrict__ adj, unsigned short* __restrict__ out, int N) {
    constexpr int LPR = D / 8;
    constexpr int G   = 64 / LPR;
    constexpr int UNR = 16 / G;
    int wid  = (blockIdx.x * blockDim.x + threadIdx.x) >> 6;
    int lane = threadIdx.x & 63;
    if (wid >= N) return;
    int beg = rowc[wid];
    int deg = rowc[wid + 1] - beg;

    const int g  = lane >> (LPR == 16 ? 4 : 5);
    const int gl = lane & (LPR - 1);

    float acc[8];
    #pragma unroll
    for (int p = 0; p < 8; ++p) acc[p] = 0.0f;

    for (int base = 0; base < deg; base += 64) {
        int nb_l = (base + lane < deg) ? adj[beg + base + lane] : 0;
        int m = deg - base; if (m > 64) m = 64;
        int j = 0;
        for (; j + UNR * G <= m; j += UNR * G) {
            int nn[UNR];
            #pragma unroll
            for (int u = 0; u < UNR; ++u) nn[u] = __shfl(nb_l, j + u * G + g);
            short8 vv[UNR];
            #pragma unroll
            for (int u = 0; u < UNR; ++u)
                vv[u] = *(const short8*)(x + (size_t)nn[u] * D + gl * 8);
            #pragma unroll
            for (int u = 0; u < UNR; ++u)
                #pragma unroll
                for (int p = 0; p < 8; ++p) acc[p] += b2f((unsigned short)vv[u][p]);
        }
        for (; j < m; j += G) {
            int idx = j + g;
            int nb = __shfl(nb_l, idx);
            if (idx < m) {
                const short8 v = *(const short8*)(x + (size_t)nb * D + gl * 8);
                #pragma unroll
                for (int p = 0; p < 8; ++p) acc[p] += b2f((unsigned short)v[p]);
            }
        }
    }
    #pragma unroll
    for (int off = LPR; off < 64; off <<= 1) {
        #pragma unroll
        for (int p = 0; p < 8; ++p) acc[p] += __shfl_xor(acc[p], off);
    }
    float inv = 1.0f / (float)((deg > 0) ? deg : 1);
    if (lane < LPR) {
        unsigned short* op = out + (size_t)wid * D + lane * 8;
        short8 u;
        #pragma unroll
        for (int p = 0; p < 8; ++p) u[p] = (short)f2b(acc[p] * inv);
        *(short8*)op = u;
    }
}

// ---------- 4-matrix weight transpose: W f32 [K][256] -> Wt bf16 [256][K] ----------
__global__ void transpose_w4(const float* __restrict__ W0, const float* __restrict__ W1,
                             const float* __restrict__ W2, const float* __restrict__ W3,
                             unsigned short* __restrict__ T0, unsigned short* __restrict__ T1,
                             unsigned short* __restrict__ T2, unsigned short* __restrict__ T3,
                             int K) {
    int k = blockIdx.x;        // [0,K)
    int c = threadIdx.x;       // [0,256)
    int m = blockIdx.y;
    const float* W = (m == 0) ? W0 : (m == 1) ? W1 : (m == 2) ? W2 : W3;
    unsigned short* T = (m == 0) ? T0 : (m == 1) ? T1 : (m == 2) ? T2 : T3;
    T[(size_t)c * K + k] = f2b(W[(size_t)k * 256 + c]);
}

// ---------- fused GEMM (R5-exact): res = relu(A0@B0^T + A1@B1^T + bias) ----------
// Tile 64x256, BK=64, 4 waves. R5-proven config (R6/R7: 128x256/512thr = -95us).
template <bool F32OUT>
__global__ __launch_bounds__(256, 3)
void gemm_fused(const unsigned short* __restrict__ A0, const unsigned short* __restrict__ A1,
                const unsigned short* __restrict__ B0, const unsigned short* __restrict__ B1,
                const float* __restrict__ bias,
                float* __restrict__ outf, unsigned short* __restrict__ outb,
                int M, int K) {
    __shared__ unsigned short As[64 * 64];    // 8 KB
    __shared__ unsigned short Bs[256 * 64];   // 32 KB
    const int tid  = threadIdx.x;
    const int wave = tid >> 6, lane = tid & 63;
    const int wn   = wave;
    const int row0 = blockIdx.x * 64;

    float4v acc[4][4];
    #pragma unroll
    for (int i = 0; i < 4; ++i)
        #pragma unroll
        for (int j = 0; j < 4; ++j) acc[i][j] = (float4v){0.f, 0.f, 0.f, 0.f};

    const int r  = lane >> 3;
    const int cg = lane & 7;
    const int kchunks = K >> 6;
    const int nchunks = kchunks * 2;

    for (int c = 0; c < nchunks; ++c) {
        const unsigned short* Aseg = (c < kchunks) ? A0 : A1;
        const unsigned short* Bseg = (c < kchunks) ? B0 : B1;
        const int k0 = ((c < kchunks) ? c : c - kchunks) << 6;

        if (c) __syncthreads();
        {   // stage A: 64 rows; 16 rows per wave
            int rr = wave * 16;
            const unsigned short* gp = Aseg + (size_t)(row0 + rr + r) * K + k0 + cg * 8;
            unsigned short* lp = As + rr * 64;
            if (row0 + rr + r < M)     gload_lds16(gp, lp);
            if (row0 + rr + 8 + r < M) gload_lds16(gp + 8 * (size_t)K, lp + 8 * 64);
        }
        {   // stage B: 256 rows; 64 rows per wave
            int rr = wave * 64;
            const unsigned short* gp = Bseg + (size_t)(rr + r) * K + k0 + cg * 8;
            unsigned short* lp = Bs + rr * 64;
            #pragma unroll
            for (int i = 0; i < 8; ++i)
                gload_lds16(gp + (size_t)(i * 8) * K, lp + i * 8 * 64);
        }
        __syncthreads();

        const int q8 = (lane >> 4) * 8;
        const int l15 = lane & 15;
        #pragma unroll
        for (int kk = 0; kk <= 32; kk += 32) {
            short8 af[4], bf[4];
            #pragma unroll
            for (int f = 0; f < 4; ++f)
                af[f] = *(const short8*)(As + (f * 16 + l15) * 64 + kk + q8);
            #pragma unroll
            for (int f = 0; f < 4; ++f)
                bf[f] = *(const short8*)(Bs + (wn * 64 + f * 16 + l15) * 64 + kk + q8);
            #pragma unroll
            for (int fm = 0; fm < 4; ++fm)
                #pragma unroll
                for (int fn = 0; fn < 4; ++fn)
                    acc[fm][fn] = __builtin_amdgcn_mfma_f32_16x16x32_bf16(
                        af[fm], bf[fn], acc[fm][fn], 0, 0, 0);
        }
    }

    // epilogue: C/D layout col=lane&15, row=(lane>>4)*4+reg  [verified m89/m91]
    const int l15 = lane & 15;
    const int rq  = (lane >> 4) * 4;
    #pragma unroll
    for (int fn = 0; fn < 4; ++fn) {
        int col = wn * 64 + fn * 16 + l15;
        float bv = bias[col];
        #pragma unroll
        for (int fm = 0; fm < 4; ++fm) {
            #pragma unroll
            for (int rg = 0; rg < 4; ++rg) {
                int row = row0 + fm * 16 + rq + rg;
                if (row < M) {
                    float v = fmaxf(acc[fm][fn][rg] + bv, 0.0f);
                    if (F32OUT) outf[(size_t)row * 256 + col] = v;
                    else        outb[(size_t)row * 256 + col] = f2b(v);
                }
            }
        }
    }
}

// ---------- launcher ----------
extern "C" void kernel_launch(void* const* d_in, const int* in_sizes, int n_in,
                              void* d_out, int out_size, void* d_ws, size_t ws_size,
                              hipStream_t stream) {
    const int DIN = 128, H = 256;
    const int N = in_sizes[0] / DIN;
    const int E = in_sizes[2] / 2;

    const float* xh = (const float*)d_in[0];
    const float* xb = (const float*)d_in[1];
    const int* ei  = (const int*)d_in[2];
    const int* src = ei;
    const int* dst = ei + E;
    const float* h1Wl = (const float*)d_in[3];
    const float* h1Wr = (const float*)d_in[4];
    const float* h1b  = (const float*)d_in[5];
    const float* h2Wl = (const float*)d_in[6];
    const float* h2Wr = (const float*)d_in[7];
    const float* h2b  = (const float*)d_in[8];
    const float* b1Wl = (const float*)d_in[9];
    const float* b1Wr = (const float*)d_in[10];
    const float* b1b  = (const float*)d_in[11];
    const float* b2Wl = (const float*)d_in[12];
    const float* b2Wr = (const float*)d_in[13];
    const float* b2b  = (const float*)d_in[14];

    float* outH = (float*)d_out;
    float* outB = outH + (size_t)N * H;

    const int BLK = 256;
    dim3 blk(BLK);

    // bf16 tail: weights + xbf[(N+1)*DIN] + aggbf[N*H] + hbf[(N+1)*H]
    const size_t bfElems = (size_t)4 * DIN * H + (size_t)4 * H * H
                         + (size_t)(N + 1) * DIN + (size_t)N * H + (size_t)(N + 1) * H;
    const size_t bfBytes = bfElems * 2 + 64;

    // ELL needs: cnt 2N + adj 2*64*N ints
    const size_t needELL = ((size_t)2 * N + (size_t)128 * N) * 4 + bfBytes;
    const bool useELL = ws_size >= needELL;

    const int* rc_h; const int* rc_b; const int* ajh; const int* ajb;
    uintptr_t intEnd;

    // compute bf16 pointers after int region
    if (useELL) intEnd = (uintptr_t)((int*)d_ws + (size_t)2 * N + (size_t)128 * N);
    else        intEnd = (uintptr_t)((int*)d_ws + (size_t)4 * N + 2 * (N + 1) + 256 + (size_t)2 * E);
    uintptr_t up = (intEnd + 63) & ~(uintptr_t)63;
    unsigned short* wtp = (unsigned short*)up;
    unsigned short* t_h1l = wtp; wtp += DIN * H;
    unsigned short* t_h1r = wtp; wtp += DIN * H;
    unsigned short* t_h2l = wtp; wtp += H * H;
    unsigned short* t_h2r = wtp; wtp += H * H;
    unsigned short* t_b1l = wtp; wtp += DIN * H;
    unsigned short* t_b1r = wtp; wtp += DIN * H;
    unsigned short* t_b2l = wtp; wtp += H * H;
    unsigned short* t_b2r = wtp; wtp += H * H;
    unsigned short* xbf   = wtp; wtp += (size_t)(N + 1) * DIN;   // row N = zeros
    unsigned short* aggbf = wtp; wtp += (size_t)N * H;
    unsigned short* hbf   = wtp;                                  // row N = zeros

    if (useELL) {
        int* cnt_h = (int*)d_ws;
        int* cnt_b = cnt_h + N;
        int* adj_h = cnt_b + N;
        int* adj_b = adj_h + (size_t)N * 64;

        {   // pad adj with N, zero cnt, zero sentinel rows
            size_t tot4 = (size_t)N * 16;
            int nblk = (int)((tot4 + BLK - 1) / BLK);
            init_ell<<<dim3(nblk), blk, 0, stream>>>(adj_h, adj_b, cnt_h,
                                                     xbf + (size_t)N * DIN,
                                                     hbf + (size_t)N * H, N);
        }
        const int NCH = 256;
        fill_ell_ranged<<<dim3(NCH * 8), blk, 0, stream>>>(src, dst, cnt_h, cnt_b,
                                                           adj_h, adj_b, E, N, NCH);
        rc_h = cnt_h; rc_b = cnt_b; ajh = adj_h; ajb = adj_b;
    } else {
        int* deg_h = (int*)d_ws;
        int* deg_b = deg_h + N;
        int* row_h = deg_b + N;
        int* row_b = row_h + (N + 1);
        int* cur_h = row_b + (N + 1);
        int* cur_b = cur_h + N;
        int* partial = cur_b + N;
        int* adj_h = partial + 256;
        int* adj_b = adj_h + E;

        const int P = (N + 1023) / 1024;
        hipMemsetAsync(deg_h, 0, (size_t)2 * N * sizeof(int), stream);
        count_deg<<<dim3((E + BLK - 1) / BLK), blk, 0, stream>>>(src, dst, deg_h, deg_b, E);
        scan1<<<dim3(P), blk, 0, stream>>>(deg_h, partial, N);
        scan2<<<dim3(1), blk, 0, stream>>>(partial, P);
        scan3<<<dim3(P), blk, 0, stream>>>(deg_h, partial, row_h, N, E);
        scan1<<<dim3(P), blk, 0, stream>>>(deg_b, partial, N);
        scan2<<<dim3(1), blk, 0, stream>>>(partial, P);
        scan3<<<dim3(P), blk, 0, stream>>>(deg_b, partial, row_b, N, E);
        hipMemcpyAsync(cur_h, row_h, (size_t)N * sizeof(int), hipMemcpyDeviceToDevice, stream);
        hipMemcpyAsync(cur_b, row_b, (size_t)N * sizeof(int), hipMemcpyDeviceToDevice, stream);
        const int NCH = 256;
        fill_adj_ranged<<<dim3(NCH * 8), blk, 0, stream>>>(src, dst, cur_h, cur_b,
                                                           adj_h, adj_b, E, N, NCH);
        rc_h = row_h; rc_b = row_b; ajh = adj_h; ajb = adj_b;
    }

    // weight transposes: 2 launches (K=128 quad, K=256 quad)
    transpose_w4<<<dim3(DIN, 4), blk, 0, stream>>>(h1Wl, h1Wr, b1Wl, b1Wr,
                                                   t_h1l, t_h1r, t_b1l, t_b1r, DIN);
    transpose_w4<<<dim3(H, 4),   blk, 0, stream>>>(h2Wl, h2Wr, b2Wl, b2Wr,
                                                   t_h2l, t_h2r, t_b2l, t_b2r, H);

    dim3 nggrid((N + 3) / 4);
    dim3 ggrid((N + 63) / 64);
    int ncvt = ((size_t)N * DIN / 4 + BLK - 1) / BLK;

    // ---- human branch ----
    cvt_to_bf16<<<dim3(ncvt), blk, 0, stream>>>(xh, xbf, (size_t)N * DIN / 4);
    if (useELL) gather_mean_ell<128><<<nggrid, blk, 0, stream>>>(xbf, rc_h, ajh, aggbf, N);
    else        gather_mean<128><<<nggrid, blk, 0, stream>>>(xbf, rc_h, ajh, aggbf, N);
    gemm_fused<false><<<ggrid, blk, 0, stream>>>(aggbf, xbf, t_h1l, t_h1r, h1b,
                                                 nullptr, hbf, N, DIN);
    if (useELL) gather_mean_ell<256><<<nggrid, blk, 0, stream>>>(hbf, rc_h, ajh, aggbf, N);
    else        gather_mean<256><<<nggrid, blk, 0, stream>>>(hbf, rc_h, ajh, aggbf, N);
    gemm_fused<true><<<ggrid, blk, 0, stream>>>(aggbf, hbf, t_h2l, t_h2r, h2b,
                                                outH, nullptr, N, H);

    // ---- bacterial branch ----
    cvt_to_bf16<<<dim3(ncvt), blk, 0, stream>>>(xb, xbf, (size_t)N * DIN / 4);
    if (useELL) gather_mean_ell<128><<<nggrid, blk, 0, stream>>>(xbf, rc_b, ajb, aggbf, N);
    else        gather_mean<128><<<nggrid, blk, 0, stream>>>(xbf, rc_b, ajb, aggbf, N);
    gemm_fused<false><<<ggrid, blk, 0, stream>>>(aggbf, xbf, t_b1l, t_b1r, b1b,
                                                 nullptr, hbf, N, DIN);
    if (useELL) gather_mean_ell<256><<<nggrid, blk, 0, stream>>>(hbf, rc_b, ajb, aggbf, N);
    else        gather_mean<256><<<nggrid, blk, 0, stream>>>(hbf, rc_b, ajb, aggbf, N);
    gemm_fused<true><<<ggrid, blk, 0, stream>>>(aggbf, hbf, t_b2l, t_b2r, b2b,
                                                outB, nullptr, N, H);
}

// Round 9
// 1020.717 us; speedup vs baseline: 1.0959x; 1.0167x over previous
//
#include <hip/hip_runtime.h>
#include <stdint.h>

// ---------- types / helpers ----------
using short8  = __attribute__((ext_vector_type(8))) short;
using float4v = __attribute__((ext_vector_type(4))) float;

__device__ __forceinline__ float b2f(unsigned short u) {
    union { unsigned int i; float f; } v; v.i = ((unsigned int)u) << 16; return v.f;
}
__device__ __forceinline__ unsigned short f2b(float f) {
    union { float f; unsigned int i; } v; v.f = f;
    unsigned int x = v.i;
    unsigned int r = (x + 0x7fffu + ((x >> 16) & 1u)) >> 16;   // RNE
    return (unsigned short)r;
}
__device__ __forceinline__ void gload_lds16(const void* g, void* l) {
    __builtin_amdgcn_global_load_lds((const __attribute__((address_space(1))) void*)g,
                                     (__attribute__((address_space(3))) void*)l, 16, 0, 0);
}

// ================= ELL fill body (R5-proven; combined directions, 8-range) ==========
__device__ __forceinline__ void fill_body(const int* __restrict__ src, const int* __restrict__ dst,
                                          int* __restrict__ cnt_h, int* __restrict__ cnt_b,
                                          int* __restrict__ adj_h, int* __restrict__ adj_b,
                                          int E, int N, int bid) {
    const int NR = 8, NCH = 256;
    int r     = bid & (NR - 1);
    int chunk = bid >> 3;
    int rng = (N + NR - 1) / NR;
    int lo = r * rng;
    int hi = lo + rng; if (hi > N) hi = N;
    int per = (E + NCH - 1) / NCH;
    int e0 = chunk * per;
    int e1 = e0 + per; if (e1 > E) e1 = E;
    for (int e = e0 + (int)threadIdx.x; e < e1; e += 256) {
        int s = __builtin_nontemporal_load(src + e);
        int d = __builtin_nontemporal_load(dst + e);
        if (s >= lo && s < hi) {
            int sl = atomicAdd(cnt_h + s, 1);
            if (sl < 64) adj_h[((size_t)s << 6) + sl] = d;
        }
        if (d >= lo && d < hi) {
            int sl = atomicAdd(cnt_b + d, 1);
            if (sl < 64) adj_b[((size_t)d << 6) + sl] = s;
        }
    }
}

__global__ __launch_bounds__(256)
void fill_ell_ranged(const int* __restrict__ src, const int* __restrict__ dst,
                     int* __restrict__ cnt_h, int* __restrict__ cnt_b,
                     int* __restrict__ adj_h, int* __restrict__ adj_b, int E, int N) {
    fill_body(src, dst, cnt_h, cnt_b, adj_h, adj_b, E, N, blockIdx.x);
}

// ================= prep fat kernel: fill || cvt_h || cvt_b || transposes || sentinels ==
__global__ __launch_bounds__(256)
void prep(const int* __restrict__ src, const int* __restrict__ dst,
          int* __restrict__ cnt_h, int* __restrict__ cnt_b,
          int* __restrict__ adj_h, int* __restrict__ adj_b, int E, int N,
          const float* __restrict__ xh, unsigned short* __restrict__ xbf_h,
          const float* __restrict__ xb, unsigned short* __restrict__ xbf_b,
          const float* __restrict__ h1Wl, const float* __restrict__ h1Wr,
          const float* __restrict__ b1Wl, const float* __restrict__ b1Wr,
          const float* __restrict__ h2Wl, const float* __restrict__ h2Wr,
          const float* __restrict__ b2Wl, const float* __restrict__ b2Wr,
          unsigned short* __restrict__ t_h1l, unsigned short* __restrict__ t_h1r,
          unsigned short* __restrict__ t_b1l, unsigned short* __restrict__ t_b1r,
          unsigned short* __restrict__ t_h2l, unsigned short* __restrict__ t_h2r,
          unsigned short* __restrict__ t_b2l, unsigned short* __restrict__ t_b2r,
          unsigned short* __restrict__ h_h, unsigned short* __restrict__ h_b) {
    const int FB = 2048;
    const int n4 = N * 32;                     // N*128/4 float4 groups
    const int CB = (n4 + 255) / 256;
    int bid = blockIdx.x;
    int tid = threadIdx.x;

    if (bid < FB) {                            // ---- fill role ----
        fill_body(src, dst, cnt_h, cnt_b, adj_h, adj_b, E, N, bid);
        return;
    }
    bid -= FB;
    if (bid < 2 * CB) {                        // ---- cvt roles ----
        const float* in = (bid < CB) ? xh : xb;
        unsigned short* out = (bid < CB) ? xbf_h : xbf_b;
        int b2 = (bid < CB) ? bid : bid - CB;
        size_t t = (size_t)b2 * 256 + tid;
        if (t < (size_t)n4) {
            const float4 v = *(const float4*)(in + t * 4);
            ushort4 u;
            u.x = f2b(v.x); u.y = f2b(v.y); u.z = f2b(v.z); u.w = f2b(v.w);
            *(ushort4*)(out + t * 4) = u;
        }
        return;
    }
    bid -= 2 * CB;
    if (bid < 512) {                           // ---- transpose K=128 (4 mats) ----
        int m = bid >> 7, k = bid & 127;
        const float* W = (m == 0) ? h1Wl : (m == 1) ? h1Wr : (m == 2) ? b1Wl : b1Wr;
        unsigned short* T = (m == 0) ? t_h1l : (m == 1) ? t_h1r : (m == 2) ? t_b1l : t_b1r;
        T[(size_t)tid * 128 + k] = f2b(W[(size_t)k * 256 + tid]);
        return;
    }
    bid -= 512;
    if (bid < 1024) {                          // ---- transpose K=256 (4 mats) ----
        int m = bid >> 8, k = bid & 255;
        const float* W = (m == 0) ? h2Wl : (m == 1) ? h2Wr : (m == 2) ? b2Wl : b2Wr;
        unsigned short* T = (m == 0) ? t_h2l : (m == 1) ? t_h2r : (m == 2) ? t_b2l : t_b2r;
        T[(size_t)tid * 256 + k] = f2b(W[(size_t)k * 256 + tid]);
        return;
    }
    // ---- sentinel role (1 block): zero row N of each feature buffer ----
    if (tid < 128) {
        xbf_h[(size_t)N * 128 + tid] = 0;
        xbf_b[(size_t)N * 128 + tid] = 0;
    }
    h_h[(size_t)N * 256 + tid] = 0;
    h_b[(size_t)N * 256 + tid] = 0;
}

// ---------- gather body: branch-free via in-register sentinel select ----------
template <int D>
__device__ __forceinline__ void gather_body(const unsigned short* __restrict__ x,
                                            const int* __restrict__ cnt,
                                            const int* __restrict__ adj,
                                            unsigned short* __restrict__ out,
                                            int N, int bid) {
    constexpr int LPR = D / 8;
    constexpr int G   = 64 / LPR;
    constexpr int STEP = 16;
    constexpr int UNR = STEP / G;
    int wave = (int)threadIdx.x >> 6;
    int lane = (int)threadIdx.x & 63;
    int wid = bid * 4 + wave;
    if (wid >= N) return;
    int c = cnt[wid];
    int deg = (c < 64) ? c : 64;
    int nb_l = adj[((size_t)wid << 6) + lane];     // slots >= deg hold garbage: selected away

    const int g  = lane >> (LPR == 16 ? 4 : 5);
    const int gl = lane & (LPR - 1);

    float acc[8];
    #pragma unroll
    for (int p = 0; p < 8; ++p) acc[p] = 0.0f;

    int rounds = (deg + STEP - 1) >> 4;            // <= 4
    for (int t = 0; t < rounds; ++t) {
        int j = t * STEP;
        int nn[UNR];
        #pragma unroll
        for (int u = 0; u < UNR; ++u) {
            int idx = j + u * G + g;
            int v = __shfl(nb_l, idx);
            nn[u] = (idx < deg) ? v : N;           // sentinel -> zero row
        }
        short8 vv[UNR];
        #pragma unroll
        for (int u = 0; u < UNR; ++u)
            vv[u] = *(const short8*)(x + (size_t)nn[u] * D + gl * 8);
        #pragma unroll
        for (int u = 0; u < UNR; ++u)
            #pragma unroll
            for (int p = 0; p < 8; ++p) acc[p] += b2f((unsigned short)vv[u][p]);
    }
    #pragma unroll
    for (int off = LPR; off < 64; off <<= 1) {
        #pragma unroll
        for (int p = 0; p < 8; ++p) acc[p] += __shfl_xor(acc[p], off);
    }
    float inv = 1.0f / (float)((deg > 0) ? deg : 1);
    if (lane < LPR) {
        unsigned short* op = out + (size_t)wid * D + lane * 8;
        short8 u;
        #pragma unroll
        for (int p = 0; p < 8; ++p) u[p] = (short)f2b(acc[p] * inv);
        *(short8*)op = u;
    }
}

template <int D>
__global__ __launch_bounds__(256)
void gather_mean_sel(const unsigned short* __restrict__ x, const int* __restrict__ cnt,
                     const int* __restrict__ adj, unsigned short* __restrict__ out, int N) {
    gather_body<D>(x, cnt, adj, out, N, blockIdx.x);
}

// ---------- gemm body (R5-exact inner; 64x256 tile, BK=64, 4 waves) ----------
template <bool F32OUT>
__device__ __forceinline__ void gemm_body(const unsigned short* __restrict__ A0,
                                          const unsigned short* __restrict__ A1,
                                          const unsigned short* __restrict__ B0,
                                          const unsigned short* __restrict__ B1,
                                          const float* __restrict__ bias,
                                          float* __restrict__ outf,
                                          unsigned short* __restrict__ outb,
                                          int M, int K,
                                          unsigned short* As, unsigned short* Bs, int bid) {
    const int tid  = threadIdx.x;
    const int wave = tid >> 6, lane = tid & 63;
    const int wn   = wave;
    const int row0 = bid * 64;

    float4v acc[4][4];
    #pragma unroll
    for (int i = 0; i < 4; ++i)
        #pragma unroll
        for (int j = 0; j < 4; ++j) acc[i][j] = (float4v){0.f, 0.f, 0.f, 0.f};

    const int r  = lane >> 3;
    const int cg = lane & 7;
    const int kchunks = K >> 6;
    const int nchunks = kchunks * 2;

    for (int c = 0; c < nchunks; ++c) {
        const unsigned short* Aseg = (c < kchunks) ? A0 : A1;
        const unsigned short* Bseg = (c < kchunks) ? B0 : B1;
        const int k0 = ((c < kchunks) ? c : c - kchunks) << 6;

        if (c) __syncthreads();
        {   // stage A: 64 rows; 16 rows per wave
            int rr = wave * 16;
            const unsigned short* gp = Aseg + (size_t)(row0 + rr + r) * K + k0 + cg * 8;
            unsigned short* lp = As + rr * 64;
            if (row0 + rr + r < M)     gload_lds16(gp, lp);
            if (row0 + rr + 8 + r < M) gload_lds16(gp + 8 * (size_t)K, lp + 8 * 64);
        }
        {   // stage B: 256 rows; 64 rows per wave
            int rr = wave * 64;
            const unsigned short* gp = Bseg + (size_t)(rr + r) * K + k0 + cg * 8;
            unsigned short* lp = Bs + rr * 64;
            #pragma unroll
            for (int i = 0; i < 8; ++i)
                gload_lds16(gp + (size_t)(i * 8) * K, lp + i * 8 * 64);
        }
        __syncthreads();

        const int q8 = (lane >> 4) * 8;
        const int l15 = lane & 15;
        #pragma unroll
        for (int kk = 0; kk <= 32; kk += 32) {
            short8 af[4], bf[4];
            #pragma unroll
            for (int f = 0; f < 4; ++f)
                af[f] = *(const short8*)(As + (f * 16 + l15) * 64 + kk + q8);
            #pragma unroll
            for (int f = 0; f < 4; ++f)
                bf[f] = *(const short8*)(Bs + (wn * 64 + f * 16 + l15) * 64 + kk + q8);
            #pragma unroll
            for (int fm = 0; fm < 4; ++fm)
                #pragma unroll
                for (int fn = 0; fn < 4; ++fn)
                    acc[fm][fn] = __builtin_amdgcn_mfma_f32_16x16x32_bf16(
                        af[fm], bf[fn], acc[fm][fn], 0, 0, 0);
        }
    }

    // epilogue: C/D layout col=lane&15, row=(lane>>4)*4+reg  [verified m89/m91]
    const int l15 = lane & 15;
    const int rq  = (lane >> 4) * 4;
    #pragma unroll
    for (int fn = 0; fn < 4; ++fn) {
        int col = wn * 64 + fn * 16 + l15;
        float bv = bias[col];
        #pragma unroll
        for (int fm = 0; fm < 4; ++fm) {
            #pragma unroll
            for (int rg = 0; rg < 4; ++rg) {
                int row = row0 + fm * 16 + rq + rg;
                if (row < M) {
                    float v = fmaxf(acc[fm][fn][rg] + bv, 0.0f);
                    if (F32OUT) outf[(size_t)row * 256 + col] = v;
                    else        outb[(size_t)row * 256 + col] = f2b(v);
                }
            }
        }
    }
}

template <bool F32OUT>
__global__ __launch_bounds__(256, 3)
void gemm_fused(const unsigned short* __restrict__ A0, const unsigned short* __restrict__ A1,
                const unsigned short* __restrict__ B0, const unsigned short* __restrict__ B1,
                const float* __restrict__ bias,
                float* __restrict__ outf, unsigned short* __restrict__ outb, int M, int K) {
    __shared__ unsigned short As[64 * 64];
    __shared__ unsigned short Bs[256 * 64];
    gemm_body<F32OUT>(A0, A1, B0, B1, bias, outf, outb, M, K, As, Bs, blockIdx.x);
}

// ---------- fat kernel: gemm (blocks < gemmBlocks) || gather (rest) ----------
template <bool F32OUT, int DG>
__global__ __launch_bounds__(256, 3)
void fused_gg(const unsigned short* __restrict__ A0, const unsigned short* __restrict__ A1,
              const unsigned short* __restrict__ B0, const unsigned short* __restrict__ B1,
              const float* __restrict__ bias,
              float* __restrict__ outf, unsigned short* __restrict__ outb, int M, int K,
              const unsigned short* __restrict__ gx, const int* __restrict__ gcnt,
              const int* __restrict__ gadj, unsigned short* __restrict__ gout,
              int N, int gemmBlocks) {
    __shared__ unsigned short As[64 * 64];
    __shared__ unsigned short Bs[256 * 64];
    int bid = blockIdx.x;
    if (bid < gemmBlocks) {
        gemm_body<F32OUT>(A0, A1, B0, B1, bias, outf, outb, M, K, As, Bs, bid);
    } else {
        gather_body<DG>(gx, gcnt, gadj, gout, N, bid - gemmBlocks);
    }
}

// ---------- fallback-only plain kernels ----------
__global__ void cvt_to_bf16(const float* __restrict__ in, unsigned short* __restrict__ out,
                            size_t n4) {
    size_t t = (size_t)blockIdx.x * blockDim.x + threadIdx.x;
    if (t >= n4) return;
    const float4 v = *(const float4*)(in + t * 4);
    ushort4 u;
    u.x = f2b(v.x); u.y = f2b(v.y); u.z = f2b(v.z); u.w = f2b(v.w);
    *(ushort4*)(out + t * 4) = u;
}
__global__ void transpose_w4(const float* __restrict__ W0, const float* __restrict__ W1,
                             const float* __restrict__ W2, const float* __restrict__ W3,
                             unsigned short* __restrict__ T0, unsigned short* __restrict__ T1,
                             unsigned short* __restrict__ T2, unsigned short* __restrict__ T3,
                             int K) {
    int k = blockIdx.x;
    int c = threadIdx.x;
    int m = blockIdx.y;
    const float* W = (m == 0) ? W0 : (m == 1) ? W1 : (m == 2) ? W2 : W3;
    unsigned short* T = (m == 0) ? T0 : (m == 1) ? T1 : (m == 2) ? T2 : T3;
    T[(size_t)c * K + k] = f2b(W[(size_t)k * 256 + c]);
}

// ---------- launcher ----------
extern "C" void kernel_launch(void* const* d_in, const int* in_sizes, int n_in,
                              void* d_out, int out_size, void* d_ws, size_t ws_size,
                              hipStream_t stream) {
    const int DIN = 128, H = 256;
    const int N = in_sizes[0] / DIN;
    const int E = in_sizes[2] / 2;

    const float* xh = (const float*)d_in[0];
    const float* xb = (const float*)d_in[1];
    const int* ei  = (const int*)d_in[2];
    const int* src = ei;
    const int* dst = ei + E;
    const float* h1Wl = (const float*)d_in[3];
    const float* h1Wr = (const float*)d_in[4];
    const float* h1b  = (const float*)d_in[5];
    const float* h2Wl = (const float*)d_in[6];
    const float* h2Wr = (const float*)d_in[7];
    const float* h2b  = (const float*)d_in[8];
    const float* b1Wl = (const float*)d_in[9];
    const float* b1Wr = (const float*)d_in[10];
    const float* b1b  = (const float*)d_in[11];
    const float* b2Wl = (const float*)d_in[12];
    const float* b2Wr = (const float*)d_in[13];
    const float* b2b  = (const float*)d_in[14];

    float* outH = (float*)d_out;
    float* outB = outH + (size_t)N * H;

    const int BLK = 256;
    dim3 blk(BLK);

    // ---- int region (ELL) ----
    int* cnt_h = (int*)d_ws;
    int* cnt_b = cnt_h + N;
    int* adj_h = cnt_b + N;
    int* adj_b = adj_h + (size_t)N * 64;
    uintptr_t intEnd = (uintptr_t)(adj_b + (size_t)N * 64);
    uintptr_t up = (intEnd + 63) & ~(uintptr_t)63;
    unsigned short* wtp = (unsigned short*)up;
    unsigned short* t_h1l = wtp; wtp += DIN * H;
    unsigned short* t_h1r = wtp; wtp += DIN * H;
    unsigned short* t_h2l = wtp; wtp += H * H;
    unsigned short* t_h2r = wtp; wtp += H * H;
    unsigned short* t_b1l = wtp; wtp += DIN * H;
    unsigned short* t_b1r = wtp; wtp += DIN * H;
    unsigned short* t_b2l = wtp; wtp += H * H;
    unsigned short* t_b2r = wtp; wtp += H * H;

    // parallel-path buffers
    const size_t xrow = (size_t)(N + 1) * DIN;      // bf16 elems
    const size_t arow = (size_t)N * H;
    const size_t hrow = (size_t)(N + 1) * H;
    size_t parElems = 2 * xrow + 2 * arow + 2 * hrow;
    size_t needPAR = ((uintptr_t)wtp + parElems * 2) - (uintptr_t)d_ws;
    const bool usePAR = ws_size >= needPAR;

    const int GB = (N + 63) / 64;
    const int NB = (N + 3) / 4;
    const int n4 = N * (DIN / 4);
    const int CB = (n4 + 255) / 256;

    if (usePAR) {
        unsigned short* xbf_h = wtp;          wtp += xrow;
        unsigned short* xbf_b = wtp;          wtp += xrow;
        unsigned short* agg_h = wtp;          wtp += arow;
        unsigned short* agg_b = wtp;          wtp += arow;
        unsigned short* h_h   = wtp;          wtp += hrow;
        unsigned short* h_b   = wtp;

        hipMemsetAsync(cnt_h, 0, (size_t)2 * N * sizeof(int), stream);
        // prep: fill || cvt_h || cvt_b || transposes || sentinels
        int prepGrid = 2048 + 2 * CB + 512 + 1024 + 1;
        prep<<<dim3(prepGrid), blk, 0, stream>>>(src, dst, cnt_h, cnt_b, adj_h, adj_b, E, N,
                                                 xh, xbf_h, xb, xbf_b,
                                                 h1Wl, h1Wr, b1Wl, b1Wr,
                                                 h2Wl, h2Wr, b2Wl, b2Wr,
                                                 t_h1l, t_h1r, t_b1l, t_b1r,
                                                 t_h2l, t_h2r, t_b2l, t_b2r,
                                                 h_h, h_b);
        // D1: gather_h1 (alone)
        gather_mean_sel<128><<<dim3(NB), blk, 0, stream>>>(xbf_h, cnt_h, adj_h, agg_h, N);
        // D2: gemm_h1 || gather_b1
        fused_gg<false, 128><<<dim3(GB + NB), blk, 0, stream>>>(
            agg_h, xbf_h, t_h1l, t_h1r, h1b, nullptr, h_h, N, DIN,
            xbf_b, cnt_b, adj_b, agg_b, N, GB);
        // D3: gemm_b1 || gather_h2
        fused_gg<false, 256><<<dim3(GB + NB), blk, 0, stream>>>(
            agg_b, xbf_b, t_b1l, t_b1r, b1b, nullptr, h_b, N, DIN,
            h_h, cnt_h, adj_h, agg_h, N, GB);
        // D4: gemm_h2 || gather_b2
        fused_gg<true, 256><<<dim3(GB + NB), blk, 0, stream>>>(
            agg_h, h_h, t_h2l, t_h2r, h2b, outH, nullptr, N, H,
            h_b, cnt_b, adj_b, agg_b, N, GB);
        // D5: gemm_b2 (alone)
        gemm_fused<true><<<dim3(GB), blk, 0, stream>>>(agg_b, h_b, t_b2l, t_b2r, b2b,
                                                       outB, nullptr, N, H);
    } else {
        // ---- serial ELL fallback (shared buffers) ----
        unsigned short* xbf   = wtp;          wtp += xrow;
        unsigned short* aggbf = wtp;          wtp += arow;
        unsigned short* hbf   = wtp;

        hipMemsetAsync(cnt_h, 0, (size_t)2 * N * sizeof(int), stream);
        hipMemsetAsync(xbf + (size_t)N * DIN, 0, DIN * sizeof(unsigned short), stream);
        hipMemsetAsync(hbf + (size_t)N * H, 0, H * sizeof(unsigned short), stream);
        fill_ell_ranged<<<dim3(2048), blk, 0, stream>>>(src, dst, cnt_h, cnt_b,
                                                        adj_h, adj_b, E, N);
        transpose_w4<<<dim3(DIN, 4), blk, 0, stream>>>(h1Wl, h1Wr, b1Wl, b1Wr,
                                                       t_h1l, t_h1r, t_b1l, t_b1r, DIN);
        transpose_w4<<<dim3(H, 4),   blk, 0, stream>>>(h2Wl, h2Wr, b2Wl, b2Wr,
                                                       t_h2l, t_h2r, t_b2l, t_b2r, H);
        int ncvt = (n4 + BLK - 1) / BLK;
        // human
        cvt_to_bf16<<<dim3(ncvt), blk, 0, stream>>>(xh, xbf, (size_t)n4);
        gather_mean_sel<128><<<dim3(NB), blk, 0, stream>>>(xbf, cnt_h, adj_h, aggbf, N);
        gemm_fused<false><<<dim3(GB), blk, 0, stream>>>(aggbf, xbf, t_h1l, t_h1r, h1b,
                                                        nullptr, hbf, N, DIN);
        gather_mean_sel<256><<<dim3(NB), blk, 0, stream>>>(hbf, cnt_h, adj_h, aggbf, N);
        gemm_fused<true><<<dim3(GB), blk, 0, stream>>>(aggbf, hbf, t_h2l, t_h2r, h2b,
                                                       outH, nullptr, N, H);
        // bacterial
        cvt_to_bf16<<<dim3(ncvt), blk, 0, stream>>>(xb, xbf, (size_t)n4);
        gather_mean_sel<128><<<dim3(NB), blk, 0, stream>>>(xbf, cnt_b, adj_b, aggbf, N);
        gemm_fused<false><<<dim3(GB), blk, 0, stream>>>(aggbf, xbf, t_b1l, t_b1r, b1b,
                                                        nullptr, hbf, N, DIN);
        gather_mean_sel<256><<<dim3(NB), blk, 0, stream>>>(hbf, cnt_b, adj_b, aggbf, N);
        gemm_fused<true><<<dim3(GB), blk, 0, stream>>>(aggbf, hbf, t_b2l, t_b2r, b2b,
                                                       outB, nullptr, N, H);
    }
}